// Round 3
// baseline (3948.664 us; speedup 1.0000x reference)
//
#include <hip/hip_runtime.h>

// Problem constants (fixed shape)
#define GDIM 256
#define DDIM 20
#define HID 150
#define HP 160            // padded hidden (quarters of 40, float4-exact)
#define QH 40             // per-thread quarter of hidden
#define QH4 10            // float4s per quarter
#define KMAX 250
#define NMAX 2000

// workspace layout (float offsets)
#define OFF_U   0
#define OFF_V   (OFF_U + NMAX*HP)          // 320000
#define OFF_D   (OFF_V + NMAX*HP)          // 640000
#define OFF_WC  (OFF_D + 9*HP)             // 641440
#define OFF_W2  (OFF_WC + GDIM*HP)         // 682400
#define OFF_W3  (OFF_W2 + HP*HP)           // 708000
#define OFF_B2  (OFF_W3 + HP)              // 708160  (end 708320 floats = 2.83MB)

// ---------------------------------------------------------------------------
// Kernel 1a: U[i] = i_g @ W1[0:256] + b1 ;  V[j] = j_g @ W1[256:512]  (HP-padded)
// ---------------------------------------------------------------------------
__global__ void precompute_uv(const float* __restrict__ g_i,
                              const float* __restrict__ W1,
                              const float* __restrict__ b1,
                              float* __restrict__ ws, int N) {
  int t = blockIdx.x * blockDim.x + threadIdx.x;
  int total = N * HP;
  bool isV = false;
  if (t >= total) { t -= total; isV = true; }
  if (t >= total) return;
  int r = t / HP, c = t - (t / HP) * HP;
  float acc = 0.f;
  if (c < HID) {
    const float* w = W1 + (isV ? GDIM * HID : 0) + c;
    const float* g = g_i + (size_t)r * GDIM;
#pragma unroll 8
    for (int k = 0; k < GDIM; k++) acc = fmaf(g[k], w[(size_t)k * HID], acc);
    if (!isV) acc += b1[c];
  }
  ws[(isV ? OFF_V : OFF_U) + (size_t)r * HP + c] = acc;
}

// ---------------------------------------------------------------------------
// Kernel 1b: distance table + padded weight copies (zeros in pads)
// ---------------------------------------------------------------------------
__global__ void precompute_tabs(const float* __restrict__ dist_embed,
                                const float* __restrict__ W1,
                                const float* __restrict__ W2,
                                const float* __restrict__ b2,
                                const float* __restrict__ W3,
                                float* __restrict__ ws) {
  int t = blockIdx.x * blockDim.x + threadIdx.x;
  if (t < 9 * HP) {                                  // D[d] = dist_embed[d] @ W1[768:788]
    int d = t / HP, c = t - d * HP;
    float a = 0.f;
    if (c < HID) {
#pragma unroll
      for (int k = 0; k < DDIM; k++)
        a = fmaf(dist_embed[d * DDIM + k], W1[(size_t)(3 * GDIM + k) * HID + c], a);
    }
    ws[OFF_D + t] = a;
    return;
  }
  t -= 9 * HP;
  if (t < GDIM * HP) {                               // Wc rows (W1[512:768]), col-padded
    int k = t / HP, c = t - k * HP;
    ws[OFF_WC + t] = (c < HID) ? W1[(size_t)(2 * GDIM + k) * HID + c] : 0.f;
    return;
  }
  t -= GDIM * HP;
  if (t < HP * HP) {                                 // W2, row+col padded
    int k = t / HP, c = t - k * HP;
    ws[OFF_W2 + t] = (k < HID && c < HID) ? W2[(size_t)k * HID + c] : 0.f;
    return;
  }
  t -= HP * HP;
  if (t < HP) { ws[OFF_W3 + t] = (t < HID) ? W3[t] : 0.f; return; }
  t -= HP;
  if (t < HP) { ws[OFF_B2 + t] = (t < HID) ? b2[t] : 0.f; return; }
}

// ---------------------------------------------------------------------------
// Kernel 2: pair MLP, 4 lanes cooperate per pair (lane = q*16+p, 16 pairs/wave).
// Each lane owns h1[40q..40q+39] and acc2[40q..40q+39] in REGISTERS (no LDS).
// Layer-2 cross-quarter values come via __shfl from the statically-indexed
// owner register (40-deep full unroll keeps indices compile-time).
// ---------------------------------------------------------------------------
__global__ __launch_bounds__(256, 3)
void pair_mlp(const float* __restrict__ g_i,
              const float* __restrict__ ms,
              const int* __restrict__ mid,
              const int* __restrict__ aid,
              const int* __restrict__ dist,
              const float* __restrict__ b3,
              const float* __restrict__ ws,
              float* __restrict__ out2, int P) {
  int tid  = threadIdx.x;
  int wave = tid >> 6;
  int lane = tid & 63;
  int p    = lane & 15;          // pair sub-index within wave
  int q    = lane >> 4;          // hidden quarter 0..3
  int pair = blockIdx.x * 64 + wave * 16 + p;
  int pc   = (pair < P) ? pair : (P - 1);

  int i = mid[pc], j = aid[pc], d = dist[pc];
  int didx = (d >= 1) + (d >= 2) + (d >= 3) + (d >= 4) +
             (d >= 8) + (d >= 16) + (d >= 32) + (d >= 64);

  // ---- layer 1 init: U[i]+V[j]+D[didx], this thread's quarter ----
  const float4* Uq = (const float4*)(ws + OFF_U + (size_t)i    * HP + QH * q);
  const float4* Vq = (const float4*)(ws + OFF_V + (size_t)j    * HP + QH * q);
  const float4* Dq = (const float4*)(ws + OFF_D + (size_t)didx * HP + QH * q);

  float h1[QH];
#pragma unroll
  for (int c4 = 0; c4 < QH4; c4++) {
    float4 u = Uq[c4], v = Vq[c4], dd = Dq[c4];
    h1[4 * c4 + 0] = u.x + v.x + dd.x;
    h1[4 * c4 + 1] = u.y + v.y + dd.y;
    h1[4 * c4 + 2] = u.z + v.z + dd.z;
    h1[4 * c4 + 3] = u.w + v.w + dd.w;
  }

  // ---- layer 1 bilinear: h1[c] += sum_k i_g[k]*j_g[k]*Wc[k][c] ----
  const float4* I4 = (const float4*)(g_i + (size_t)i * GDIM);
  const float4* J4 = (const float4*)(g_i + (size_t)j * GDIM);
  const float*  wc = ws + OFF_WC + QH * q;

  for (int k4 = 0; k4 < GDIM / 4; k4++) {
    float4 iv = I4[k4], jv = J4[k4];
    float xs[4] = { iv.x * jv.x, iv.y * jv.y, iv.z * jv.z, iv.w * jv.w };
    const float* wk = wc + (size_t)(4 * k4) * HP;
#pragma unroll
    for (int kk = 0; kk < 4; kk++) {
      float x = xs[kk];
      const float4* w4 = (const float4*)(wk + (size_t)kk * HP);
#pragma unroll
      for (int c4 = 0; c4 < QH4; c4++) {
        float4 w = w4[c4];
        h1[4 * c4 + 0] = fmaf(x, w.x, h1[4 * c4 + 0]);
        h1[4 * c4 + 1] = fmaf(x, w.y, h1[4 * c4 + 1]);
        h1[4 * c4 + 2] = fmaf(x, w.z, h1[4 * c4 + 2]);
        h1[4 * c4 + 3] = fmaf(x, w.w, h1[4 * c4 + 3]);
      }
    }
  }
#pragma unroll
  for (int c = 0; c < QH; c++) h1[c] = fmaxf(h1[c], 0.f);

  // ---- layer 2: acc2q[c] = b2[c] + sum_k h1[k] * W2[k][c] ----
  float a2[QH];
  const float4* B2q = (const float4*)(ws + OFF_B2 + QH * q);
#pragma unroll
  for (int c4 = 0; c4 < QH4; c4++) {
    float4 b = B2q[c4];
    a2[4 * c4 + 0] = b.x; a2[4 * c4 + 1] = b.y;
    a2[4 * c4 + 2] = b.z; a2[4 * c4 + 3] = b.w;
  }

  for (int sq = 0; sq < 4; sq++) {                 // source quarter (owner lane group)
    int src = sq * 16 + p;
    const float* w2k = ws + OFF_W2 + (size_t)(sq * QH) * HP + QH * q;
#pragma unroll
    for (int kk = 0; kk < QH; kk++) {              // static index into h1 (reg file)
      float x = __shfl(h1[kk], src, 64);
      const float4* w4 = (const float4*)(w2k + (size_t)kk * HP);
#pragma unroll
      for (int c4 = 0; c4 < QH4; c4++) {
        float4 w = w4[c4];
        a2[4 * c4 + 0] = fmaf(x, w.x, a2[4 * c4 + 0]);
        a2[4 * c4 + 1] = fmaf(x, w.y, a2[4 * c4 + 1]);
        a2[4 * c4 + 2] = fmaf(x, w.z, a2[4 * c4 + 2]);
        a2[4 * c4 + 3] = fmaf(x, w.w, a2[4 * c4 + 3]);
      }
    }
  }

  // ---- layer 3 (relu fused) + cross-quarter reduce ----
  const float4* W3q = (const float4*)(ws + OFF_W3 + QH * q);
  float s = 0.f;
#pragma unroll
  for (int c4 = 0; c4 < QH4; c4++) {
    float4 w = W3q[c4];
    s = fmaf(fmaxf(a2[4 * c4 + 0], 0.f), w.x, s);
    s = fmaf(fmaxf(a2[4 * c4 + 1], 0.f), w.y, s);
    s = fmaf(fmaxf(a2[4 * c4 + 2], 0.f), w.z, s);
    s = fmaf(fmaxf(a2[4 * c4 + 3], 0.f), w.w, s);
  }
  s += __shfl_xor(s, 16, 64);
  s += __shfl_xor(s, 32, 64);

  if (q == 0 && pair < P) {
    float val = ms[i] + ms[j] + s + b3[0];
    ((float2*)out2)[pair] = make_float2(0.f, val);
  }
}

// ---------------------------------------------------------------------------
// Kernel 3: per-group softmax rows (wave per row)  [unchanged — passed, ~16 µs]
// ---------------------------------------------------------------------------
__global__ __launch_bounds__(64, 1)
void softmax_rows(const float* __restrict__ out2,
                  float* __restrict__ probs, int G) {
  int b = blockIdx.x;
  int t = threadIdx.x;
  if (b == 0) {
    for (int pos = t; pos <= KMAX; pos += 64)
      probs[pos] = (pos == 0) ? 1.0f : 1000.0f;
    return;
  }
  int g = b - 1;
  int L = (g + 1 < KMAX) ? g + 1 : KMAX;
  int base = (g <= KMAX) ? g * (g + 1) / 2
                         : KMAX * (KMAX + 1) / 2 + (g - KMAX) * KMAX;
  float mx = 0.f;                               // includes implicit 0.0 at pos L
  for (int pos = t; pos < L; pos += 64)
    mx = fmaxf(mx, out2[2 * (base + pos) + 1]);
#pragma unroll
  for (int off = 32; off >= 1; off >>= 1) mx = fmaxf(mx, __shfl_xor(mx, off));

  float sum = (t == 0) ? expf(-mx) : 0.f;
  for (int pos = t; pos < L; pos += 64)
    sum += expf(out2[2 * (base + pos) + 1] - mx);
#pragma unroll
  for (int off = 32; off >= 1; off >>= 1) sum += __shfl_xor(sum, off);
  float inv = 1.f / sum;

  float* row = probs + (size_t)(g + 1) * (KMAX + 1);
  for (int pos = t; pos <= KMAX; pos += 64) {
    float v;
    if (pos < L)       v = expf(out2[2 * (base + pos) + 1] - mx) * inv;
    else if (pos == L) v = expf(-mx) * inv;
    else               v = 1000.0f;
    row[pos] = v;
  }
}

// ---------------------------------------------------------------------------
extern "C" void kernel_launch(void* const* d_in, const int* in_sizes, int n_in,
                              void* d_out, int out_size, void* d_ws, size_t ws_size,
                              hipStream_t stream) {
  const float* g_i        = (const float*)d_in[0];
  const float* ms         = (const float*)d_in[1];
  const float* dist_embed = (const float*)d_in[2];
  const float* W1         = (const float*)d_in[3];
  const float* b1         = (const float*)d_in[4];
  const float* W2         = (const float*)d_in[5];
  const float* b2         = (const float*)d_in[6];
  const float* W3         = (const float*)d_in[7];
  const float* b3         = (const float*)d_in[8];
  const int* mid          = (const int*)d_in[9];
  const int* aid          = (const int*)d_in[10];
  const int* dist         = (const int*)d_in[11];

  int N = in_sizes[0] / GDIM;     // 2000
  int P = in_sizes[9];            // 468625
  int G = in_sizes[14];           // 1999

  float* ws    = (float*)d_ws;
  float* probs = (float*)d_out;
  float* out2  = (float*)d_out + (size_t)(G + 1) * (KMAX + 1);

  int tot_uv = 2 * N * HP;
  precompute_uv<<<(tot_uv + 255) / 256, 256, 0, stream>>>(g_i, W1, b1, ws, N);
  int tot_tab = 9 * HP + GDIM * HP + HP * HP + 2 * HP;
  precompute_tabs<<<(tot_tab + 255) / 256, 256, 0, stream>>>(dist_embed, W1, W2, b2, W3, ws);
  pair_mlp<<<(P + 63) / 64, 256, 0, stream>>>(g_i, ms, mid, aid, dist, b3, ws, out2, P);
  softmax_rows<<<G + 1, 64, 0, stream>>>(out2, probs, G);
}

// Round 5
// 3705.370 us; speedup vs baseline: 1.0657x; 1.0657x over previous
//
#include <hip/hip_runtime.h>

// Problem constants (fixed shape)
#define GDIM 256
#define DDIM 20
#define HID 150
#define HP 160            // padded hidden (quarters of 40, float4-exact)
#define QH 40             // per-thread quarter of hidden
#define QH4 10            // float4s per quarter
#define KMAX 250
#define NMAX 2000
#define LROW 164          // LDS row stride (floats): 164%32=4 -> 2-way max on reads

// workspace layout (float offsets)
#define OFF_U   0
#define OFF_V   (OFF_U + NMAX*HP)
#define OFF_D   (OFF_V + NMAX*HP)
#define OFF_WC  (OFF_D + 9*HP)
#define OFF_W2  (OFF_WC + GDIM*HP)
#define OFF_W3  (OFF_W2 + HP*HP)
#define OFF_B2  (OFF_W3 + HP)

// ---------------------------------------------------------------------------
// Kernel 1a: U[i] = i_g @ W1[0:256] + b1 ;  V[j] = j_g @ W1[256:512]  (HP-pad)
// ---------------------------------------------------------------------------
__global__ void precompute_uv(const float* __restrict__ g_i,
                              const float* __restrict__ W1,
                              const float* __restrict__ b1,
                              float* __restrict__ ws, int N) {
  int t = blockIdx.x * blockDim.x + threadIdx.x;
  int total = N * HP;
  bool isV = false;
  if (t >= total) { t -= total; isV = true; }
  if (t >= total) return;
  int r = t / HP, c = t - (t / HP) * HP;
  float acc = 0.f;
  if (c < HID) {
    const float* w = W1 + (isV ? GDIM * HID : 0) + c;
    const float* g = g_i + (size_t)r * GDIM;
#pragma unroll 8
    for (int k = 0; k < GDIM; k++) acc = fmaf(g[k], w[(size_t)k * HID], acc);
    if (!isV) acc += b1[c];
  }
  ws[(isV ? OFF_V : OFF_U) + (size_t)r * HP + c] = acc;
}

// ---------------------------------------------------------------------------
// Kernel 1b: distance table + padded weight copies (zeros in pads)
// ---------------------------------------------------------------------------
__global__ void precompute_tabs(const float* __restrict__ dist_embed,
                                const float* __restrict__ W1,
                                const float* __restrict__ W2,
                                const float* __restrict__ b2,
                                const float* __restrict__ W3,
                                float* __restrict__ ws) {
  int t = blockIdx.x * blockDim.x + threadIdx.x;
  if (t < 9 * HP) {
    int d = t / HP, c = t - d * HP;
    float a = 0.f;
    if (c < HID) {
#pragma unroll
      for (int k = 0; k < DDIM; k++)
        a = fmaf(dist_embed[d * DDIM + k], W1[(size_t)(3 * GDIM + k) * HID + c], a);
    }
    ws[OFF_D + t] = a;
    return;
  }
  t -= 9 * HP;
  if (t < GDIM * HP) {
    int k = t / HP, c = t - k * HP;
    ws[OFF_WC + t] = (c < HID) ? W1[(size_t)(2 * GDIM + k) * HID + c] : 0.f;
    return;
  }
  t -= GDIM * HP;
  if (t < HP * HP) {
    int k = t / HP, c = t - k * HP;
    ws[OFF_W2 + t] = (k < HID && c < HID) ? W2[(size_t)k * HID + c] : 0.f;
    return;
  }
  t -= HP * HP;
  if (t < HP) { ws[OFF_W3 + t] = (t < HID) ? W3[t] : 0.f; return; }
  t -= HP;
  if (t < HP) { ws[OFF_B2 + t] = (t < HID) ? b2[t] : 0.f; return; }
}

// ---------------------------------------------------------------------------
// Kernel 2: pair MLP. 4 lanes/pair (lane = q*16+p), 16 pairs per 64-thread
// block (1 wave). h1 goes through a 10.5 KB per-wave LDS buffer so layer 2
// is a compact dynamic k-loop (no giant unroll, no shuffle static-indexing,
// no spill). No barriers: LDS region is wave-private.
// ---------------------------------------------------------------------------
__global__ __launch_bounds__(64, 3)
void pair_mlp(const float* __restrict__ g_i,
              const float* __restrict__ ms,
              const int* __restrict__ mid,
              const int* __restrict__ aid,
              const int* __restrict__ dist,
              const float* __restrict__ b3,
              const float* __restrict__ ws,
              float* __restrict__ out2, int P) {
  __shared__ float h1s[16 * LROW];     // [pair p][k], row stride LROW
  int lane = threadIdx.x;
  int p    = lane & 15;                // pair sub-index within wave
  int q    = lane >> 4;                // hidden quarter 0..3
  int pair = blockIdx.x * 16 + p;
  int pc   = (pair < P) ? pair : (P - 1);

  int i = mid[pc], j = aid[pc], d = dist[pc];
  int didx = (d >= 1) + (d >= 2) + (d >= 3) + (d >= 4) +
             (d >= 8) + (d >= 16) + (d >= 32) + (d >= 64);

  // ---- layer 1 init: U[i]+V[j]+D[didx], this lane's quarter ----
  const float4* Uq = (const float4*)(ws + OFF_U + (size_t)i    * HP + QH * q);
  const float4* Vq = (const float4*)(ws + OFF_V + (size_t)j    * HP + QH * q);
  const float4* Dq = (const float4*)(ws + OFF_D + (size_t)didx * HP + QH * q);

  float h1[QH];
#pragma unroll
  for (int c4 = 0; c4 < QH4; c4++) {
    float4 u = Uq[c4], v = Vq[c4], dd = Dq[c4];
    h1[4 * c4 + 0] = u.x + v.x + dd.x;
    h1[4 * c4 + 1] = u.y + v.y + dd.y;
    h1[4 * c4 + 2] = u.z + v.z + dd.z;
    h1[4 * c4 + 3] = u.w + v.w + dd.w;
  }

  // ---- layer 1 bilinear: h1[c] += sum_k i_g[k]*j_g[k]*Wc[k][c] ----
  const float4* I4 = (const float4*)(g_i + (size_t)i * GDIM);
  const float4* J4 = (const float4*)(g_i + (size_t)j * GDIM);
  const float*  wc = ws + OFF_WC + QH * q;

#pragma unroll 1
  for (int k4 = 0; k4 < GDIM / 4; k4++) {
    float4 iv = I4[k4], jv = J4[k4];
    float xs[4] = { iv.x * jv.x, iv.y * jv.y, iv.z * jv.z, iv.w * jv.w };
    const float* wk = wc + (size_t)(4 * k4) * HP;
#pragma unroll
    for (int kk = 0; kk < 4; kk++) {
      float x = xs[kk];
      const float4* w4 = (const float4*)(wk + (size_t)kk * HP);
#pragma unroll
      for (int c4 = 0; c4 < QH4; c4++) {
        float4 w = w4[c4];
        h1[4 * c4 + 0] = fmaf(x, w.x, h1[4 * c4 + 0]);
        h1[4 * c4 + 1] = fmaf(x, w.y, h1[4 * c4 + 1]);
        h1[4 * c4 + 2] = fmaf(x, w.z, h1[4 * c4 + 2]);
        h1[4 * c4 + 3] = fmaf(x, w.w, h1[4 * c4 + 3]);
      }
    }
  }

  // relu -> wave-private LDS (row p, cols 40q..40q+39)
  float* hrow = h1s + p * LROW + QH * q;
#pragma unroll
  for (int c4 = 0; c4 < QH4; c4++) {
    float4 v;
    v.x = fmaxf(h1[4 * c4 + 0], 0.f);
    v.y = fmaxf(h1[4 * c4 + 1], 0.f);
    v.z = fmaxf(h1[4 * c4 + 2], 0.f);
    v.w = fmaxf(h1[4 * c4 + 3], 0.f);
    ((float4*)hrow)[c4] = v;
  }

  // ---- layer 2: a2[c] = b2[c] + sum_k h1row[k] * W2[k][c] ----
  float a2[QH];
  const float4* B2q = (const float4*)(ws + OFF_B2 + QH * q);
#pragma unroll
  for (int c4 = 0; c4 < QH4; c4++) {
    float4 b = B2q[c4];
    a2[4 * c4 + 0] = b.x; a2[4 * c4 + 1] = b.y;
    a2[4 * c4 + 2] = b.z; a2[4 * c4 + 3] = b.w;
  }

  const float* xrow = h1s + p * LROW;
  const float* w2q  = ws + OFF_W2 + QH * q;
#pragma unroll 1
  for (int k4 = 0; k4 < HP / 4; k4++) {
    float4 x4 = ((const float4*)xrow)[k4];        // ds_read_b128, 2-way max
    float xs[4] = { x4.x, x4.y, x4.z, x4.w };
    const float* wk = w2q + (size_t)(4 * k4) * HP;
#pragma unroll
    for (int kk = 0; kk < 4; kk++) {
      float x = xs[kk];
      const float4* w4 = (const float4*)(wk + (size_t)kk * HP);
#pragma unroll
      for (int c4 = 0; c4 < QH4; c4++) {
        float4 w = w4[c4];
        a2[4 * c4 + 0] = fmaf(x, w.x, a2[4 * c4 + 0]);
        a2[4 * c4 + 1] = fmaf(x, w.y, a2[4 * c4 + 1]);
        a2[4 * c4 + 2] = fmaf(x, w.z, a2[4 * c4 + 2]);
        a2[4 * c4 + 3] = fmaf(x, w.w, a2[4 * c4 + 3]);
      }
    }
  }

  // ---- layer 3 (relu fused) + cross-quarter reduce ----
  const float4* W3q = (const float4*)(ws + OFF_W3 + QH * q);
  float s = 0.f;
#pragma unroll
  for (int c4 = 0; c4 < QH4; c4++) {
    float4 w = W3q[c4];
    s = fmaf(fmaxf(a2[4 * c4 + 0], 0.f), w.x, s);
    s = fmaf(fmaxf(a2[4 * c4 + 1], 0.f), w.y, s);
    s = fmaf(fmaxf(a2[4 * c4 + 2], 0.f), w.z, s);
    s = fmaf(fmaxf(a2[4 * c4 + 3], 0.f), w.w, s);
  }
  s += __shfl_xor(s, 16, 64);
  s += __shfl_xor(s, 32, 64);

  if (q == 0 && pair < P) {
    float val = ms[i] + ms[j] + s + b3[0];
    ((float2*)out2)[pair] = make_float2(0.f, val);
  }
}

// ---------------------------------------------------------------------------
// Kernel 3: per-group softmax rows (wave per row)  [unchanged — known good]
// ---------------------------------------------------------------------------
__global__ __launch_bounds__(64, 1)
void softmax_rows(const float* __restrict__ out2,
                  float* __restrict__ probs, int G) {
  int b = blockIdx.x;
  int t = threadIdx.x;
  if (b == 0) {
    for (int pos = t; pos <= KMAX; pos += 64)
      probs[pos] = (pos == 0) ? 1.0f : 1000.0f;
    return;
  }
  int g = b - 1;
  int L = (g + 1 < KMAX) ? g + 1 : KMAX;
  int base = (g <= KMAX) ? g * (g + 1) / 2
                         : KMAX * (KMAX + 1) / 2 + (g - KMAX) * KMAX;
  float mx = 0.f;                               // includes implicit 0.0 at pos L
  for (int pos = t; pos < L; pos += 64)
    mx = fmaxf(mx, out2[2 * (base + pos) + 1]);
#pragma unroll
  for (int off = 32; off >= 1; off >>= 1) mx = fmaxf(mx, __shfl_xor(mx, off));

  float sum = (t == 0) ? expf(-mx) : 0.f;
  for (int pos = t; pos < L; pos += 64)
    sum += expf(out2[2 * (base + pos) + 1] - mx);
#pragma unroll
  for (int off = 32; off >= 1; off >>= 1) sum += __shfl_xor(sum, off);
  float inv = 1.f / sum;

  float* row = probs + (size_t)(g + 1) * (KMAX + 1);
  for (int pos = t; pos <= KMAX; pos += 64) {
    float v;
    if (pos < L)       v = expf(out2[2 * (base + pos) + 1] - mx) * inv;
    else if (pos == L) v = expf(-mx) * inv;
    else               v = 1000.0f;
    row[pos] = v;
  }
}

// ---------------------------------------------------------------------------
extern "C" void kernel_launch(void* const* d_in, const int* in_sizes, int n_in,
                              void* d_out, int out_size, void* d_ws, size_t ws_size,
                              hipStream_t stream) {
  const float* g_i        = (const float*)d_in[0];
  const float* ms         = (const float*)d_in[1];
  const float* dist_embed = (const float*)d_in[2];
  const float* W1         = (const float*)d_in[3];
  const float* b1         = (const float*)d_in[4];
  const float* W2         = (const float*)d_in[5];
  const float* b2         = (const float*)d_in[6];
  const float* W3         = (const float*)d_in[7];
  const float* b3         = (const float*)d_in[8];
  const int* mid          = (const int*)d_in[9];
  const int* aid          = (const int*)d_in[10];
  const int* dist         = (const int*)d_in[11];

  int N = in_sizes[0] / GDIM;     // 2000
  int P = in_sizes[9];            // 468625
  int G = in_sizes[14];           // 1999

  float* ws    = (float*)d_ws;
  float* probs = (float*)d_out;
  float* out2  = (float*)d_out + (size_t)(G + 1) * (KMAX + 1);

  int tot_uv = 2 * N * HP;
  precompute_uv<<<(tot_uv + 255) / 256, 256, 0, stream>>>(g_i, W1, b1, ws, N);
  int tot_tab = 9 * HP + GDIM * HP + HP * HP + 2 * HP;
  precompute_tabs<<<(tot_tab + 255) / 256, 256, 0, stream>>>(dist_embed, W1, W2, b2, W3, ws);
  pair_mlp<<<(P + 15) / 16, 64, 0, stream>>>(g_i, ms, mid, aid, dist, b3, ws, out2, P);
  softmax_rows<<<G + 1, 64, 0, stream>>>(out2, probs, G);
}

// Round 6
// 605.753 us; speedup vs baseline: 6.5186x; 6.1170x over previous
//
#include <hip/hip_runtime.h>

#define GDIM 256
#define HID 150
#define HP 160
#define KMAX 250
#define NMAX 2000
#define P_TOT 468625

typedef __attribute__((ext_vector_type(8))) short bf16x8;
typedef __attribute__((ext_vector_type(4))) float f32x4;

// ws layout (float offsets for fp32 part; ushort arrays after)
#define FU 0
#define FV (FU + NMAX*HP)            // 320000
#define FD (FV + NMAX*HP)            // 640000
#define FW3 (FD + 9*HP)              // 641440
#define FB2 (FW3 + HP)               // 641600
#define FEND (FB2 + HP)              // 641760 floats
// ushort regions start at FEND*2 ushorts
#define UWCH 0
#define UWCL (UWCH + HP*GDIM)        // 40960
#define UW2H (UWCL + HP*GDIM)
#define UW2L (UW2H + HP*HP)          // +25600

__device__ __forceinline__ unsigned short f2bf(float x) {
  unsigned u = __float_as_uint(x);
  unsigned r = u + 0x7fffu + ((u >> 16) & 1u);
  return (unsigned short)(r >> 16);
}
__device__ __forceinline__ float bf2f(unsigned short h) {
  return __uint_as_float(((unsigned)h) << 16);
}

// ---------------------------------------------------------------------------
// U[i] = i_g @ W1[0:256] + b1 ; V[j] = j_g @ W1[256:512]   (HP-padded fp32)
// ---------------------------------------------------------------------------
__global__ void precompute_uv(const float* __restrict__ g_i,
                              const float* __restrict__ W1,
                              const float* __restrict__ b1,
                              float* __restrict__ ws, int N) {
  int t = blockIdx.x * blockDim.x + threadIdx.x;
  int total = N * HP;
  bool isV = false;
  if (t >= total) { t -= total; isV = true; }
  if (t >= total) return;
  int r = t / HP, c = t - (t / HP) * HP;
  float acc = 0.f;
  if (c < HID) {
    const float* w = W1 + (isV ? GDIM * HID : 0) + c;
    const float* g = g_i + (size_t)r * GDIM;
#pragma unroll 8
    for (int k = 0; k < GDIM; k++) acc = fmaf(g[k], w[(size_t)k * HID], acc);
    if (!isV) acc += b1[c];
  }
  ws[(isV ? FV : FU) + (size_t)r * HP + c] = acc;
}

// ---------------------------------------------------------------------------
// D table, W3/b2 padded, and split-bf16 transposed weights WcT / W2T (hi+lo)
// ---------------------------------------------------------------------------
__global__ void precompute_tabs(const float* __restrict__ dist_embed,
                                const float* __restrict__ W1,
                                const float* __restrict__ W2,
                                const float* __restrict__ b2,
                                const float* __restrict__ W3,
                                float* __restrict__ wsf) {
  unsigned short* wsu = (unsigned short*)(wsf + FEND);
  int t = blockIdx.x * blockDim.x + threadIdx.x;
  if (t < 9 * HP) {                                    // D[d][c]
    int d = t / HP, c = t - d * HP;
    float a = 0.f;
    if (c < HID) {
#pragma unroll
      for (int k = 0; k < 20; k++)
        a = fmaf(dist_embed[d * 20 + k], W1[(size_t)(768 + k) * HID + c], a);
    }
    wsf[FD + t] = a;
    return;
  }
  t -= 9 * HP;
  if (t < HP) { wsf[FW3 + t] = (t < HID) ? W3[t] : 0.f; return; }
  t -= HP;
  if (t < HP) { wsf[FB2 + t] = (t < HID) ? b2[t] : 0.f; return; }
  t -= HP;
  if (t < HP * GDIM) {                                 // WcT[n][k] = W1[512+k][n]
    int n = t / GDIM, k = t - n * GDIM;
    float w = (n < HID) ? W1[(size_t)(512 + k) * HID + n] : 0.f;
    unsigned short h = f2bf(w);
    wsu[UWCH + t] = h;
    wsu[UWCL + t] = f2bf(w - bf2f(h));
    return;
  }
  t -= HP * GDIM;
  if (t < HP * HP) {                                   // W2T[n][k] = W2[k][n]
    int n = t / HP, k = t - n * HP;
    float w = (n < HID && k < HID) ? W2[(size_t)k * HID + n] : 0.f;
    unsigned short h = f2bf(w);
    wsu[UW2H + t] = h;
    wsu[UW2L + t] = f2bf(w - bf2f(h));
    return;
  }
}

// ---------------------------------------------------------------------------
// Pair MLP via MFMA. 1 wave/block, 32 pairs/wave (2 row-tiles of 16).
// GEMM1: X(32x256) @ Wc(256x160), split-bf16 (3 mfma). Bias+relu epilogue.
// H -> LDS (hi|lo packed u32, XOR-swizzled 8-dword blocks). GEMM2: H @ W2.
// Epilogue2: +b2, relu, dot W3, +ms_i+ms_j+b3.
// ---------------------------------------------------------------------------
__device__ __forceinline__ void split8(const float* __restrict__ pi,
                                       const float* __restrict__ pj,
                                       bf16x8& hi, bf16x8& lo) {
  float4 a0 = *(const float4*)(pi);
  float4 a1 = *(const float4*)(pi + 4);
  float4 b0 = *(const float4*)(pj);
  float4 b1 = *(const float4*)(pj + 4);
  float x[8] = {a0.x * b0.x, a0.y * b0.y, a0.z * b0.z, a0.w * b0.w,
                a1.x * b1.x, a1.y * b1.y, a1.z * b1.z, a1.w * b1.w};
#pragma unroll
  for (int e = 0; e < 8; e++) {
    unsigned short h = f2bf(x[e]);
    hi[e] = (short)h;
    lo[e] = (short)f2bf(x[e] - bf2f(h));
  }
}

__global__ __launch_bounds__(64, 2)
void pair_mlp(const float* __restrict__ g_i,
              const float* __restrict__ ms,
              const int* __restrict__ mid,
              const int* __restrict__ aid,
              const int* __restrict__ dist,
              const float* __restrict__ b3,
              const float* __restrict__ wsf,
              float* __restrict__ out2, int P) {
  __shared__ unsigned int Hp[32 * 168] __attribute__((aligned(16)));
  const unsigned short* wsu = (const unsigned short*)(wsf + FEND);
  const unsigned short* WCH = wsu + UWCH;
  const unsigned short* WCL = wsu + UWCL;
  const unsigned short* W2H = wsu + UW2H;
  const unsigned short* W2L = wsu + UW2L;

  int lane = threadIdx.x;
  int c = lane & 15;        // free-dim index within 16-tile
  int g = lane >> 4;        // k-group 0..3
  int base = blockIdx.x * 32;

  // A-operand pair metadata (rows c and 16+c)
  int pa0 = base + c;       if (pa0 >= P) pa0 = P - 1;
  int pa1 = base + 16 + c;  if (pa1 >= P) pa1 = P - 1;
  const float* gI0 = g_i + (size_t)mid[pa0] * GDIM;
  const float* gJ0 = g_i + (size_t)aid[pa0] * GDIM;
  const float* gI1 = g_i + (size_t)mid[pa1] * GDIM;
  const float* gJ1 = g_i + (size_t)aid[pa1] * GDIM;

  f32x4 acc[2][10];
#pragma unroll
  for (int mt = 0; mt < 2; mt++)
#pragma unroll
    for (int ct = 0; ct < 10; ct++) acc[mt][ct] = (f32x4){0.f, 0.f, 0.f, 0.f};

  // ---------------- GEMM1: K = 256, 8 steps of 32 ----------------
  for (int kk = 0; kk < 8; kk++) {
    int ko = kk * 32 + g * 8;
    bf16x8 Ah0, Al0, Ah1, Al1;
    split8(gI0 + ko, gJ0 + ko, Ah0, Al0);
    split8(gI1 + ko, gJ1 + ko, Ah1, Al1);
#pragma unroll
    for (int ct = 0; ct < 10; ct++) {
      int boff = (16 * ct + c) * GDIM + ko;
      bf16x8 Bh = *(const bf16x8*)(WCH + boff);
      bf16x8 Bl = *(const bf16x8*)(WCL + boff);
      acc[0][ct] = __builtin_amdgcn_mfma_f32_16x16x32_bf16(Al0, Bh, acc[0][ct], 0, 0, 0);
      acc[0][ct] = __builtin_amdgcn_mfma_f32_16x16x32_bf16(Ah0, Bl, acc[0][ct], 0, 0, 0);
      acc[0][ct] = __builtin_amdgcn_mfma_f32_16x16x32_bf16(Ah0, Bh, acc[0][ct], 0, 0, 0);
      acc[1][ct] = __builtin_amdgcn_mfma_f32_16x16x32_bf16(Al1, Bh, acc[1][ct], 0, 0, 0);
      acc[1][ct] = __builtin_amdgcn_mfma_f32_16x16x32_bf16(Ah1, Bl, acc[1][ct], 0, 0, 0);
      acc[1][ct] = __builtin_amdgcn_mfma_f32_16x16x32_bf16(Ah1, Bh, acc[1][ct], 0, 0, 0);
    }
  }

  // ---------------- epilogue 1: bias + relu -> LDS (split-bf16 packed) -----
  int im[2][4], jm[2][4], dm[2][4];
#pragma unroll
  for (int mt = 0; mt < 2; mt++)
#pragma unroll
    for (int r = 0; r < 4; r++) {
      int p = base + 16 * mt + 4 * g + r;
      if (p >= P) p = P - 1;
      im[mt][r] = mid[p];
      jm[mt][r] = aid[p];
      int d = dist[p];
      dm[mt][r] = (d >= 1) + (d >= 2) + (d >= 3) + (d >= 4) +
                  (d >= 8) + (d >= 16) + (d >= 32) + (d >= 64);
    }
  const float* Ut = wsf + FU;
  const float* Vt = wsf + FV;
  const float* Dt = wsf + FD;
#pragma unroll
  for (int mt = 0; mt < 2; mt++)
#pragma unroll
    for (int ct = 0; ct < 10; ct++)
#pragma unroll
      for (int r = 0; r < 4; r++) {
        int col = 16 * ct + c;
        float bias = Ut[(size_t)im[mt][r] * HP + col] +
                     Vt[(size_t)jm[mt][r] * HP + col] +
                     Dt[dm[mt][r] * HP + col];
        float h = fmaxf(acc[mt][ct][r] + bias, 0.f);
        unsigned short hh = f2bf(h);
        unsigned short hl = f2bf(h - bf2f(hh));
        int row = 16 * mt + 4 * g + r;
        int blk = (col >> 3) ^ ((row >> 1) & 3);       // XOR swizzle, 8-dword blocks
        Hp[row * 168 + blk * 8 + (c & 7)] = ((unsigned)hl << 16) | hh;
      }
  __syncthreads();

  // ---------------- GEMM2: K = 160, 5 steps of 32 ----------------
  f32x4 acc2[2][10];
#pragma unroll
  for (int mt = 0; mt < 2; mt++)
#pragma unroll
    for (int ct = 0; ct < 10; ct++) acc2[mt][ct] = (f32x4){0.f, 0.f, 0.f, 0.f};

  for (int ks = 0; ks < 5; ks++) {
    bf16x8 A2h[2], A2l[2];
#pragma unroll
    for (int mt = 0; mt < 2; mt++) {
      int row = 16 * mt + c;
      int blk = (4 * ks + g) ^ ((row >> 1) & 3);
      const unsigned int* hp = &Hp[row * 168 + blk * 8];
      uint4 d0 = *(const uint4*)hp;
      uint4 d1 = *(const uint4*)(hp + 4);
      unsigned int dd[8] = {d0.x, d0.y, d0.z, d0.w, d1.x, d1.y, d1.z, d1.w};
#pragma unroll
      for (int e = 0; e < 8; e++) {
        A2h[mt][e] = (short)(dd[e] & 0xffffu);
        A2l[mt][e] = (short)(dd[e] >> 16);
      }
    }
#pragma unroll
    for (int ct = 0; ct < 10; ct++) {
      int boff = (16 * ct + c) * HP + ks * 32 + g * 8;
      bf16x8 Bh = *(const bf16x8*)(W2H + boff);
      bf16x8 Bl = *(const bf16x8*)(W2L + boff);
#pragma unroll
      for (int mt = 0; mt < 2; mt++) {
        acc2[mt][ct] = __builtin_amdgcn_mfma_f32_16x16x32_bf16(A2l[mt], Bh, acc2[mt][ct], 0, 0, 0);
        acc2[mt][ct] = __builtin_amdgcn_mfma_f32_16x16x32_bf16(A2h[mt], Bl, acc2[mt][ct], 0, 0, 0);
        acc2[mt][ct] = __builtin_amdgcn_mfma_f32_16x16x32_bf16(A2h[mt], Bh, acc2[mt][ct], 0, 0, 0);
      }
    }
  }

  // ---------------- epilogue 2: +b2, relu, dot W3, reduce, store ----------
  float b2v[10], w3v[10];
#pragma unroll
  for (int ct = 0; ct < 10; ct++) {
    b2v[ct] = wsf[FB2 + 16 * ct + c];
    w3v[ct] = wsf[FW3 + 16 * ct + c];
  }
  float sv[2][4];
#pragma unroll
  for (int mt = 0; mt < 2; mt++)
#pragma unroll
    for (int r = 0; r < 4; r++) {
      float t = 0.f;
#pragma unroll
      for (int ct = 0; ct < 10; ct++) {
        float a = acc2[mt][ct][r] + b2v[ct];
        t = fmaf(fmaxf(a, 0.f), w3v[ct], t);
      }
      t += __shfl_xor(t, 1, 64);
      t += __shfl_xor(t, 2, 64);
      t += __shfl_xor(t, 4, 64);
      t += __shfl_xor(t, 8, 64);
      sv[mt][r] = t;
    }
  if (c == 0) {
    float b3v = b3[0];
#pragma unroll
    for (int mt = 0; mt < 2; mt++)
#pragma unroll
      for (int r = 0; r < 4; r++) {
        int p = base + 16 * mt + 4 * g + r;
        if (p < P) {
          float val = sv[mt][r] + ms[im[mt][r]] + ms[jm[mt][r]] + b3v;
          ((float2*)out2)[p] = make_float2(0.f, val);
        }
      }
  }
}

// ---------------------------------------------------------------------------
// per-group softmax rows (wave per row) — unchanged, known good
// ---------------------------------------------------------------------------
__global__ __launch_bounds__(64, 1)
void softmax_rows(const float* __restrict__ out2,
                  float* __restrict__ probs, int G) {
  int b = blockIdx.x;
  int t = threadIdx.x;
  if (b == 0) {
    for (int pos = t; pos <= KMAX; pos += 64)
      probs[pos] = (pos == 0) ? 1.0f : 1000.0f;
    return;
  }
  int g = b - 1;
  int L = (g + 1 < KMAX) ? g + 1 : KMAX;
  int base = (g <= KMAX) ? g * (g + 1) / 2
                         : KMAX * (KMAX + 1) / 2 + (g - KMAX) * KMAX;
  float mx = 0.f;
  for (int pos = t; pos < L; pos += 64)
    mx = fmaxf(mx, out2[2 * (base + pos) + 1]);
#pragma unroll
  for (int off = 32; off >= 1; off >>= 1) mx = fmaxf(mx, __shfl_xor(mx, off));

  float sum = (t == 0) ? expf(-mx) : 0.f;
  for (int pos = t; pos < L; pos += 64)
    sum += expf(out2[2 * (base + pos) + 1] - mx);
#pragma unroll
  for (int off = 32; off >= 1; off >>= 1) sum += __shfl_xor(sum, off);
  float inv = 1.f / sum;

  float* row = probs + (size_t)(g + 1) * (KMAX + 1);
  for (int pos = t; pos <= KMAX; pos += 64) {
    float v;
    if (pos < L)       v = expf(out2[2 * (base + pos) + 1] - mx) * inv;
    else if (pos == L) v = expf(-mx) * inv;
    else               v = 1000.0f;
    row[pos] = v;
  }
}

// ---------------------------------------------------------------------------
extern "C" void kernel_launch(void* const* d_in, const int* in_sizes, int n_in,
                              void* d_out, int out_size, void* d_ws, size_t ws_size,
                              hipStream_t stream) {
  const float* g_i        = (const float*)d_in[0];
  const float* ms         = (const float*)d_in[1];
  const float* dist_embed = (const float*)d_in[2];
  const float* W1         = (const float*)d_in[3];
  const float* b1         = (const float*)d_in[4];
  const float* W2         = (const float*)d_in[5];
  const float* b2         = (const float*)d_in[6];
  const float* W3         = (const float*)d_in[7];
  const float* b3         = (const float*)d_in[8];
  const int* mid          = (const int*)d_in[9];
  const int* aid          = (const int*)d_in[10];
  const int* dist         = (const int*)d_in[11];

  int N = in_sizes[0] / GDIM;     // 2000
  int P = in_sizes[9];            // 468625
  int G = in_sizes[14];           // 1999

  float* wsf   = (float*)d_ws;
  float* probs = (float*)d_out;
  float* out2  = (float*)d_out + (size_t)(G + 1) * (KMAX + 1);

  int tot_uv = 2 * N * HP;
  precompute_uv<<<(tot_uv + 255) / 256, 256, 0, stream>>>(g_i, W1, b1, wsf, N);
  int tot_tab = 9 * HP + 2 * HP + HP * GDIM + HP * HP;
  precompute_tabs<<<(tot_tab + 255) / 256, 256, 0, stream>>>(dist_embed, W1, W2, b2, W3, wsf);
  pair_mlp<<<(P + 31) / 32, 64, 0, stream>>>(g_i, ms, mid, aid, dist, b3, wsf, out2, P);
  softmax_rows<<<G + 1, 64, 0, stream>>>(out2, probs, G);
}

// Round 7
// 492.637 us; speedup vs baseline: 8.0154x; 1.2296x over previous
//
#include <hip/hip_runtime.h>
#include <hip/hip_bf16.h>

#define GDIM 256
#define HID 150
#define HP 160
#define KMAX 250
#define NMAX 2000

typedef __attribute__((ext_vector_type(8))) short bf16x8;
typedef __attribute__((ext_vector_type(4))) float f32x4;

// ws layout: fp32 region, then bf16 (ushort) region
#define FU 0
#define FV (FU + NMAX*HP)            // 320000
#define FD (FV + NMAX*HP)            // 640000
#define FW3 (FD + 9*HP)              // 641440
#define FB2 (FW3 + HP)               // 641600
#define FEND (FB2 + HP)              // 641760 floats
#define UWC 0                        // WcT bf16 [HP][GDIM]
#define UW2 (UWC + HP*GDIM)          // W2T bf16 [HP][HP]

__device__ __forceinline__ short cvt_bf(float x) {
  __hip_bfloat16 h = __float2bfloat16(x);     // RNE; compiler may pack to v_cvt_pk_bf16_f32
  return *reinterpret_cast<short*>(&h);
}

// ---------------------------------------------------------------------------
// U[i] = i_g @ W1[0:256] + b1 ; V[j] = j_g @ W1[256:512]   (fp32, HP-padded)
// ---------------------------------------------------------------------------
__global__ void precompute_uv(const float* __restrict__ g_i,
                              const float* __restrict__ W1,
                              const float* __restrict__ b1,
                              float* __restrict__ ws, int N) {
  int t = blockIdx.x * blockDim.x + threadIdx.x;
  int total = N * HP;
  bool isV = false;
  if (t >= total) { t -= total; isV = true; }
  if (t >= total) return;
  int r = t / HP, c = t - (t / HP) * HP;
  float acc = 0.f;
  if (c < HID) {
    const float* w = W1 + (isV ? GDIM * HID : 0) + c;
    const float* g = g_i + (size_t)r * GDIM;
#pragma unroll 8
    for (int k = 0; k < GDIM; k++) acc = fmaf(g[k], w[(size_t)k * HID], acc);
    if (!isV) acc += b1[c];
  }
  ws[(isV ? FV : FU) + (size_t)r * HP + c] = acc;
}

// ---------------------------------------------------------------------------
// D table, W3/b2 (fp32 padded), bf16 transposed weights WcT / W2T
// ---------------------------------------------------------------------------
__global__ void precompute_tabs(const float* __restrict__ dist_embed,
                                const float* __restrict__ W1,
                                const float* __restrict__ W2,
                                const float* __restrict__ b2,
                                const float* __restrict__ W3,
                                float* __restrict__ wsf) {
  unsigned short* wsu = (unsigned short*)(wsf + FEND);
  int t = blockIdx.x * blockDim.x + threadIdx.x;
  if (t < 9 * HP) {                                    // D[d][c]
    int d = t / HP, c = t - d * HP;
    float a = 0.f;
    if (c < HID) {
#pragma unroll
      for (int k = 0; k < 20; k++)
        a = fmaf(dist_embed[d * 20 + k], W1[(size_t)(768 + k) * HID + c], a);
    }
    wsf[FD + t] = a;
    return;
  }
  t -= 9 * HP;
  if (t < HP) { wsf[FW3 + t] = (t < HID) ? W3[t] : 0.f; return; }
  t -= HP;
  if (t < HP) { wsf[FB2 + t] = (t < HID) ? b2[t] : 0.f; return; }
  t -= HP;
  if (t < HP * GDIM) {                                 // WcT[n][k] = W1[512+k][n]
    int n = t / GDIM, k = t - n * GDIM;
    float w = (n < HID) ? W1[(size_t)(512 + k) * HID + n] : 0.f;
    wsu[UWC + t] = (unsigned short)cvt_bf(w);
    return;
  }
  t -= HP * GDIM;
  if (t < HP * HP) {                                   // W2T[n][k] = W2[k][n]
    int n = t / HP, k = t - n * HP;
    float w = (n < HID && k < HID) ? W2[(size_t)k * HID + n] : 0.f;
    wsu[UW2 + t] = (unsigned short)cvt_bf(w);
    return;
  }
}

// ---------------------------------------------------------------------------
// Pair MLP via MFMA, plain bf16 operands (1 mfma/tile). 1 wave/block, 32
// pairs/wave. GEMM1: X(32x256)@Wc -> bias+relu -> Hp (bf16 LDS, 10.75 KB,
// XOR-swizzled rows) -> GEMM2: H(32x160)@W2 -> +b2, relu, dot W3, store.
// LDS halved vs split-bf16 => 15 blocks/CU (~3.75 waves/SIMD) to hide the
// L2 weight-stream latency that capped round 6 at 1.75 waves/SIMD.
// ---------------------------------------------------------------------------
__global__ __launch_bounds__(64, 3)
void pair_mlp(const float* __restrict__ g_i,
              const float* __restrict__ ms,
              const int* __restrict__ mid,
              const int* __restrict__ aid,
              const int* __restrict__ dist,
              const float* __restrict__ b3,
              const float* __restrict__ wsf,
              float* __restrict__ out2, int P) {
  __shared__ short Hp[32 * 168] __attribute__((aligned(16)));   // bf16, row stride 336 B
  const unsigned short* wsu = (const unsigned short*)(wsf + FEND);
  const unsigned short* WC  = wsu + UWC;
  const unsigned short* W2T = wsu + UW2;

  int lane = threadIdx.x;
  int c = lane & 15;        // free-dim index within 16-tile
  int g = lane >> 4;        // k-group 0..3
  int base = blockIdx.x * 32;

  int pa0 = base + c;       if (pa0 >= P) pa0 = P - 1;
  int pa1 = base + 16 + c;  if (pa1 >= P) pa1 = P - 1;
  const float* gI0 = g_i + (size_t)mid[pa0] * GDIM;
  const float* gJ0 = g_i + (size_t)aid[pa0] * GDIM;
  const float* gI1 = g_i + (size_t)mid[pa1] * GDIM;
  const float* gJ1 = g_i + (size_t)aid[pa1] * GDIM;

  f32x4 acc[2][10];
#pragma unroll
  for (int mt = 0; mt < 2; mt++)
#pragma unroll
    for (int ct = 0; ct < 10; ct++) acc[mt][ct] = (f32x4){0.f, 0.f, 0.f, 0.f};

  // ---------------- GEMM1: K = 256, 8 steps of 32 ----------------
  for (int kk = 0; kk < 8; kk++) {
    int ko = kk * 32 + g * 8;
    bf16x8 A0, A1;
    {
      float4 a0 = *(const float4*)(gI0 + ko), a1 = *(const float4*)(gI0 + ko + 4);
      float4 b0 = *(const float4*)(gJ0 + ko), b1 = *(const float4*)(gJ0 + ko + 4);
      A0[0] = cvt_bf(a0.x * b0.x); A0[1] = cvt_bf(a0.y * b0.y);
      A0[2] = cvt_bf(a0.z * b0.z); A0[3] = cvt_bf(a0.w * b0.w);
      A0[4] = cvt_bf(a1.x * b1.x); A0[5] = cvt_bf(a1.y * b1.y);
      A0[6] = cvt_bf(a1.z * b1.z); A0[7] = cvt_bf(a1.w * b1.w);
    }
    {
      float4 a0 = *(const float4*)(gI1 + ko), a1 = *(const float4*)(gI1 + ko + 4);
      float4 b0 = *(const float4*)(gJ1 + ko), b1 = *(const float4*)(gJ1 + ko + 4);
      A1[0] = cvt_bf(a0.x * b0.x); A1[1] = cvt_bf(a0.y * b0.y);
      A1[2] = cvt_bf(a0.z * b0.z); A1[3] = cvt_bf(a0.w * b0.w);
      A1[4] = cvt_bf(a1.x * b1.x); A1[5] = cvt_bf(a1.y * b1.y);
      A1[6] = cvt_bf(a1.z * b1.z); A1[7] = cvt_bf(a1.w * b1.w);
    }
#pragma unroll
    for (int ct = 0; ct < 10; ct++) {
      bf16x8 B = *(const bf16x8*)(WC + (16 * ct + c) * GDIM + ko);
      acc[0][ct] = __builtin_amdgcn_mfma_f32_16x16x32_bf16(A0, B, acc[0][ct], 0, 0, 0);
      acc[1][ct] = __builtin_amdgcn_mfma_f32_16x16x32_bf16(A1, B, acc[1][ct], 0, 0, 0);
    }
  }

  // ---------------- epilogue 1: bias + relu -> Hp (bf16, XOR swizzle) -----
  int im[2][4], jm[2][4], dm[2][4];
#pragma unroll
  for (int mt = 0; mt < 2; mt++)
#pragma unroll
    for (int r = 0; r < 4; r++) {
      int p = base + 16 * mt + 4 * g + r;
      if (p >= P) p = P - 1;
      im[mt][r] = mid[p];
      jm[mt][r] = aid[p];
      int d = dist[p];
      dm[mt][r] = (d >= 1) + (d >= 2) + (d >= 3) + (d >= 4) +
                  (d >= 8) + (d >= 16) + (d >= 32) + (d >= 64);
    }
  const float* Ut = wsf + FU;
  const float* Vt = wsf + FV;
  const float* Dt = wsf + FD;
#pragma unroll
  for (int mt = 0; mt < 2; mt++)
#pragma unroll
    for (int ct = 0; ct < 10; ct++)
#pragma unroll
      for (int r = 0; r < 4; r++) {
        int col = 16 * ct + c;
        float bias = Ut[(size_t)im[mt][r] * HP + col] +
                     Vt[(size_t)jm[mt][r] * HP + col] +
                     Dt[dm[mt][r] * HP + col];
        float h = fmaxf(acc[mt][ct][r] + bias, 0.f);
        int row = 16 * mt + 4 * g + r;
        int bo = (row * 336 + col * 2) ^ ((row & 7) << 4);
        *(short*)((char*)Hp + bo) = cvt_bf(h);
      }
  __syncthreads();

  // ---------------- GEMM2: K = 160, 5 steps of 32 ----------------
  f32x4 acc2[2][10];
#pragma unroll
  for (int mt = 0; mt < 2; mt++)
#pragma unroll
    for (int ct = 0; ct < 10; ct++) acc2[mt][ct] = (f32x4){0.f, 0.f, 0.f, 0.f};

  for (int ks = 0; ks < 5; ks++) {
    bf16x8 A2[2];
#pragma unroll
    for (int mt = 0; mt < 2; mt++) {
      int row = 16 * mt + c;
      int bo = (row * 336 + (ks * 32 + g * 8) * 2) ^ ((row & 7) << 4);
      A2[mt] = *(const bf16x8*)((const char*)Hp + bo);
    }
#pragma unroll
    for (int ct = 0; ct < 10; ct++) {
      bf16x8 B = *(const bf16x8*)(W2T + (16 * ct + c) * HP + ks * 32 + g * 8);
      acc2[0][ct] = __builtin_amdgcn_mfma_f32_16x16x32_bf16(A2[0], B, acc2[0][ct], 0, 0, 0);
      acc2[1][ct] = __builtin_amdgcn_mfma_f32_16x16x32_bf16(A2[1], B, acc2[1][ct], 0, 0, 0);
    }
  }

  // ---------------- epilogue 2: +b2, relu, dot W3, reduce, store ----------
  float b2v[10], w3v[10];
#pragma unroll
  for (int ct = 0; ct < 10; ct++) {
    b2v[ct] = wsf[FB2 + 16 * ct + c];
    w3v[ct] = wsf[FW3 + 16 * ct + c];
  }
  float sv[2][4];
#pragma unroll
  for (int mt = 0; mt < 2; mt++)
#pragma unroll
    for (int r = 0; r < 4; r++) {
      float t = 0.f;
#pragma unroll
      for (int ct = 0; ct < 10; ct++) {
        float a = acc2[mt][ct][r] + b2v[ct];
        t = fmaf(fmaxf(a, 0.f), w3v[ct], t);
      }
      t += __shfl_xor(t, 1, 64);
      t += __shfl_xor(t, 2, 64);
      t += __shfl_xor(t, 4, 64);
      t += __shfl_xor(t, 8, 64);
      sv[mt][r] = t;
    }
  if (c == 0) {
    float b3v = b3[0];
#pragma unroll
    for (int mt = 0; mt < 2; mt++)
#pragma unroll
      for (int r = 0; r < 4; r++) {
        int p = base + 16 * mt + 4 * g + r;
        if (p < P) {
          float val = sv[mt][r] + ms[im[mt][r]] + ms[jm[mt][r]] + b3v;
          ((float2*)out2)[p] = make_float2(0.f, val);
        }
      }
  }
}

// ---------------------------------------------------------------------------
// per-group softmax rows (wave per row) — unchanged, known good
// ---------------------------------------------------------------------------
__global__ __launch_bounds__(64, 1)
void softmax_rows(const float* __restrict__ out2,
                  float* __restrict__ probs, int G) {
  int b = blockIdx.x;
  int t = threadIdx.x;
  if (b == 0) {
    for (int pos = t; pos <= KMAX; pos += 64)
      probs[pos] = (pos == 0) ? 1.0f : 1000.0f;
    return;
  }
  int g = b - 1;
  int L = (g + 1 < KMAX) ? g + 1 : KMAX;
  int base = (g <= KMAX) ? g * (g + 1) / 2
                         : KMAX * (KMAX + 1) / 2 + (g - KMAX) * KMAX;
  float mx = 0.f;
  for (int pos = t; pos < L; pos += 64)
    mx = fmaxf(mx, out2[2 * (base + pos) + 1]);
#pragma unroll
  for (int off = 32; off >= 1; off >>= 1) mx = fmaxf(mx, __shfl_xor(mx, off));

  float sum = (t == 0) ? expf(-mx) : 0.f;
  for (int pos = t; pos < L; pos += 64)
    sum += expf(out2[2 * (base + pos) + 1] - mx);
#pragma unroll
  for (int off = 32; off >= 1; off >>= 1) sum += __shfl_xor(sum, off);
  float inv = 1.f / sum;

  float* row = probs + (size_t)(g + 1) * (KMAX + 1);
  for (int pos = t; pos <= KMAX; pos += 64) {
    float v;
    if (pos < L)       v = expf(out2[2 * (base + pos) + 1] - mx) * inv;
    else if (pos == L) v = expf(-mx) * inv;
    else               v = 1000.0f;
    row[pos] = v;
  }
}

// ---------------------------------------------------------------------------
extern "C" void kernel_launch(void* const* d_in, const int* in_sizes, int n_in,
                              void* d_out, int out_size, void* d_ws, size_t ws_size,
                              hipStream_t stream) {
  const float* g_i        = (const float*)d_in[0];
  const float* ms         = (const float*)d_in[1];
  const float* dist_embed = (const float*)d_in[2];
  const float* W1         = (const float*)d_in[3];
  const float* b1         = (const float*)d_in[4];
  const float* W2         = (const float*)d_in[5];
  const float* b2         = (const float*)d_in[6];
  const float* W3         = (const float*)d_in[7];
  const float* b3         = (const float*)d_in[8];
  const int* mid          = (const int*)d_in[9];
  const int* aid          = (const int*)d_in[10];
  const int* dist         = (const int*)d_in[11];

  int N = in_sizes[0] / GDIM;     // 2000
  int P = in_sizes[9];            // 468625
  int G = in_sizes[14];           // 1999

  float* wsf   = (float*)d_ws;
  float* probs = (float*)d_out;
  float* out2  = (float*)d_out + (size_t)(G + 1) * (KMAX + 1);

  int tot_uv = 2 * N * HP;
  precompute_uv<<<(tot_uv + 255) / 256, 256, 0, stream>>>(g_i, W1, b1, wsf, N);
  int tot_tab = 9 * HP + 2 * HP + HP * GDIM + HP * HP;
  precompute_tabs<<<(tot_tab + 255) / 256, 256, 0, stream>>>(dist_embed, W1, W2, b2, W3, wsf);
  pair_mlp<<<(P + 31) / 32, 64, 0, stream>>>(g_i, ms, mid, aid, dist, b3, wsf, out2, P);
  softmax_rows<<<G + 1, 64, 0, stream>>>(out2, probs, G);
}

// Round 10
// 352.731 us; speedup vs baseline: 11.1945x; 1.3966x over previous
//
#include <hip/hip_runtime.h>
#include <hip/hip_bf16.h>

#define GDIM 256
#define HID 150
#define HP 160
#define KMAX 250
#define NMAX 2000

typedef __attribute__((ext_vector_type(8))) short bf16x8;
typedef __attribute__((ext_vector_type(4))) float f32x4;

// float ws region
#define FU   0
#define FV   (FU + NMAX*HP)
#define FD   (FV + NMAX*HP)
#define FW3  (FD + 9*HP)
#define FB2  (FW3 + HP)
#define FEND (FB2 + HP)              // 641760 floats
// ushort region after FEND: BCH[13][5120] shorts — 13 K-chunks of 10240 B,
// each [160 rows][32 k] bf16 stored in 128-B super-rows (2 rows) with
// XOR-swizzle byte ^= ((super&7)<<4). Chunks 0-7 = WcT, 8-12 = W2T.
#define CH_SH 5120
#define NCH1  8
#define NCH   13

static __device__ __forceinline__ short cvt_bf(float x) {
  __hip_bfloat16 h = __float2bfloat16(x);
  return *reinterpret_cast<short*>(&h);
}

// async global->LDS, 16 B per lane (LDS dest = wave-uniform base + lane*16)
static __device__ __forceinline__ void gl_lds16(const void* g, void* l) {
  __builtin_amdgcn_global_load_lds(
      (const __attribute__((address_space(1))) unsigned int*)g,
      (__attribute__((address_space(3))) unsigned int*)l, 16, 0, 0);
}

// ---------------------------------------------------------------------------
// U[i] = i_g @ W1[0:256] + b1 ; V[j] = j_g @ W1[256:512]   (fp32, HP-padded)
// ---------------------------------------------------------------------------
__global__ void precompute_uv(const float* __restrict__ g_i,
                              const float* __restrict__ W1,
                              const float* __restrict__ b1,
                              float* __restrict__ ws, int N) {
  int t = blockIdx.x * blockDim.x + threadIdx.x;
  int total = N * HP;
  bool isV = false;
  if (t >= total) { t -= total; isV = true; }
  if (t >= total) return;
  int r = t / HP, c = t - (t / HP) * HP;
  float acc = 0.f;
  if (c < HID) {
    const float* w = W1 + (isV ? GDIM * HID : 0) + c;
    const float* g = g_i + (size_t)r * GDIM;
#pragma unroll 8
    for (int k = 0; k < GDIM; k++) acc = fmaf(g[k], w[(size_t)k * HID], acc);
    if (!isV) acc += b1[c];
  }
  ws[(isV ? FV : FU) + (size_t)r * HP + c] = acc;
}

// ---------------------------------------------------------------------------
// D table, W3/b2 fp32 pads, and the 13 pre-swizzled bf16 B-chunks
// ---------------------------------------------------------------------------
__global__ void precompute_tabs(const float* __restrict__ dist_embed,
                                const float* __restrict__ W1,
                                const float* __restrict__ W2,
                                const float* __restrict__ b2,
                                const float* __restrict__ W3,
                                float* __restrict__ wsf) {
  unsigned short* wsu = (unsigned short*)(wsf + FEND);
  int t = blockIdx.x * blockDim.x + threadIdx.x;
  if (t < 9 * HP) {                                    // D[d][c]
    int d = t / HP, c = t - d * HP;
    float a = 0.f;
    if (c < HID) {
#pragma unroll
      for (int k = 0; k < 20; k++)
        a = fmaf(dist_embed[d * 20 + k], W1[(size_t)(768 + k) * HID + c], a);
    }
    wsf[FD + t] = a;
    return;
  }
  t -= 9 * HP;
  if (t < HP) { wsf[FW3 + t] = (t < HID) ? W3[t] : 0.f; return; }
  t -= HP;
  if (t < HP) { wsf[FB2 + t] = (t < HID) ? b2[t] : 0.f; return; }
  t -= HP;
  if (t < NCH * CH_SH) {
    // storage position (s = super-row, bs = short within 64) -> logical (n, kk)
    int ch = t / CH_SH, qs = t - ch * CH_SH;
    int s = qs >> 6, bs = qs & 63;
    int bbs = bs ^ ((s & 7) << 3);                     // undo swizzle (involution)
    int n = 2 * s + (bbs >> 5);
    int kk = bbs & 31;
    float w = 0.f;
    if (ch < NCH1) {
      int k = ch * 32 + kk;                            // Wc[k][n] = W1[512+k][n]
      if (n < HID) w = W1[(size_t)(2 * GDIM + k) * HID + n];
    } else {
      int k = (ch - NCH1) * 32 + kk;                   // W2[k][n]
      if (n < HID && k < HID) w = W2[(size_t)k * HID + n];
    }
    wsu[t] = (unsigned short)cvt_bf(w);
    return;
  }
}

// ---------------------------------------------------------------------------
// Pair MLP: 512 threads = 8 waves, 128 pairs/block (16 rows/wave).
// B shared by all waves via LDS double-buffered K-chunks (one barrier/chunk,
// __syncthreads' implicit vmcnt(0) drains the global_load_lds stage).
// H is wave-private LDS (320B stride, regionally-bijective XOR - fixes r7 bug).
// LDS 61440 B -> 2 blocks/CU -> 4 waves/SIMD.
// ---------------------------------------------------------------------------
__global__ __launch_bounds__(512, 4)
void pair_mlp(const float* __restrict__ g_i,
              const float* __restrict__ ms,
              const int* __restrict__ mid,
              const int* __restrict__ aid,
              const int* __restrict__ dist,
              const float* __restrict__ b3,
              const float* __restrict__ wsf,
              float* __restrict__ out2, int P) {
  __shared__ short Bb[2][CH_SH];       // 2 x 10240 B chunk buffers
  __shared__ short Hh[8][2560];        // per-wave H: 16 rows x 320 B
  const unsigned short* wsu = (const unsigned short*)(wsf + FEND);

  int tid = threadIdx.x;
  int wave = tid >> 6, lane = tid & 63;
  int c = lane & 15, g = lane >> 4;
  int tbase = blockIdx.x * 128;

  // A-row pointers (pair = row c of this wave's 16-row tile)
  int prow = tbase + wave * 16 + c;
  int pcA = (prow < P) ? prow : (P - 1);
  const float* gI = g_i + (size_t)mid[pcA] * GDIM;
  const float* gJ = g_i + (size_t)aid[pcA] * GDIM;

  // per-ct B byte offsets (same for every chunk; superrow XOR swizzle)
  int bOff[10];
#pragma unroll
  for (int ct = 0; ct < 10; ct++) {
    int n = 16 * ct + c;
    bOff[ct] = (n >> 1) * 128 + ((((n & 1) << 6) + g * 16) ^ (((n >> 1) & 7) << 4));
  }

  // ---- stage chunk 0, sync ----
  {
    const char* s = (const char*)(wsu);
    char* d = (char*)&Bb[0][0];
    gl_lds16(s + wave * 1024 + lane * 16, d + wave * 1024);
    if (wave < 2)
      gl_lds16(s + 8192 + wave * 1024 + lane * 16, d + 8192 + wave * 1024);
  }
  __syncthreads();

  // ================= GEMM1: chunks 0..7 (K = 256) =================
  f32x4 acc[10];
#pragma unroll
  for (int ct = 0; ct < 10; ct++) acc[ct] = (f32x4){0.f, 0.f, 0.f, 0.f};

  for (int t = 0; t < NCH1; t++) {
    {  // stage chunk t+1 into other buffer (chunks 1..8)
      const char* s = (const char*)(wsu + (size_t)(t + 1) * CH_SH);
      char* d = (char*)&Bb[(t + 1) & 1][0];
      gl_lds16(s + wave * 1024 + lane * 16, d + wave * 1024);
      if (wave < 2)
        gl_lds16(s + 8192 + wave * 1024 + lane * 16, d + 8192 + wave * 1024);
    }
    // A fragment: bf16(i_g * j_g) at k = t*32 + g*8
    int ko = t * 32 + g * 8;
    float4 i0 = *(const float4*)(gI + ko), i1 = *(const float4*)(gI + ko + 4);
    float4 j0 = *(const float4*)(gJ + ko), j1 = *(const float4*)(gJ + ko + 4);
    bf16x8 A;
    A[0] = cvt_bf(i0.x * j0.x); A[1] = cvt_bf(i0.y * j0.y);
    A[2] = cvt_bf(i0.z * j0.z); A[3] = cvt_bf(i0.w * j0.w);
    A[4] = cvt_bf(i1.x * j1.x); A[5] = cvt_bf(i1.y * j1.y);
    A[6] = cvt_bf(i1.z * j1.z); A[7] = cvt_bf(i1.w * j1.w);

    const char* Bp = (const char*)&Bb[t & 1][0];
#pragma unroll
    for (int ct = 0; ct < 10; ct++) {
      bf16x8 Bf = *(const bf16x8*)(Bp + bOff[ct]);
      acc[ct] = __builtin_amdgcn_mfma_f32_16x16x32_bf16(A, Bf, acc[ct], 0, 0, 0);
    }
    __syncthreads();   // drains vmcnt(0): chunk t+1 staged; all waves done with buf[t&1]
  }

  // ---- epilogue 1: bias + relu -> H (wave-private; regionally-bijective XOR)
  int im[4], jm[4], dm[4];
#pragma unroll
  for (int r = 0; r < 4; r++) {
    int p = tbase + wave * 16 + g * 4 + r;
    int pc = (p < P) ? p : (P - 1);
    im[r] = mid[pc]; jm[r] = aid[pc];
    int d = dist[pc];
    dm[r] = (d >= 1) + (d >= 2) + (d >= 3) + (d >= 4) +
            (d >= 8) + (d >= 16) + (d >= 32) + (d >= 64);
  }
  const float* Ut = wsf + FU;
  const float* Vt = wsf + FV;
  const float* Dt = wsf + FD;
  char* Hw = (char*)&Hh[wave][0];
#pragma unroll
  for (int ct = 0; ct < 10; ct++) {
#pragma unroll
    for (int r = 0; r < 4; r++) {
      int col = 16 * ct + c;
      float bias = Ut[(size_t)im[r] * HP + col] +
                   Vt[(size_t)jm[r] * HP + col] +
                   Dt[dm[r] * HP + col];
      float h = fmaxf(acc[ct][r] + bias, 0.f);
      int row = g * 4 + r;
      int byte = 32 * ct + 2 * c;
      int bo = (byte < 256) ? (byte ^ ((row & 7) << 4))
                            : (256 + ((byte - 256) ^ ((row & 3) << 4)));
      *(short*)(Hw + row * 320 + bo) = cvt_bf(h);
    }
  }

  // ================= GEMM2: chunks 8..12 (K = 160) =================
  f32x4 acc2[10];
#pragma unroll
  for (int ct = 0; ct < 10; ct++) acc2[ct] = (f32x4){0.f, 0.f, 0.f, 0.f};

  for (int t = NCH1; t < NCH; t++) {
    if (t + 1 < NCH) {  // stage chunk t+1
      const char* s = (const char*)(wsu + (size_t)(t + 1) * CH_SH);
      char* d = (char*)&Bb[(t + 1) & 1][0];
      gl_lds16(s + wave * 1024 + lane * 16, d + wave * 1024);
      if (wave < 2)
        gl_lds16(s + 8192 + wave * 1024 + lane * 16, d + 8192 + wave * 1024);
    }
    int ks = t - NCH1;
    int kbyte = ks * 64 + g * 16;
    int bo = (kbyte < 256) ? (kbyte ^ ((c & 7) << 4))
                           : (256 + ((kbyte - 256) ^ ((c & 3) << 4)));
    bf16x8 A2 = *(const bf16x8*)((const char*)&Hh[wave][0] + c * 320 + bo);

    const char* Bp = (const char*)&Bb[t & 1][0];
#pragma unroll
    for (int ct = 0; ct < 10; ct++) {
      bf16x8 Bf = *(const bf16x8*)(Bp + bOff[ct]);
      acc2[ct] = __builtin_amdgcn_mfma_f32_16x16x32_bf16(A2, Bf, acc2[ct], 0, 0, 0);
    }
    __syncthreads();
  }

  // ---- epilogue 2: +b2, relu, dot W3, reduce over c, store ----
  float b2v[10], w3v[10];
#pragma unroll
  for (int ct = 0; ct < 10; ct++) {
    b2v[ct] = wsf[FB2 + 16 * ct + c];
    w3v[ct] = wsf[FW3 + 16 * ct + c];
  }
  float b3v = b3[0];
#pragma unroll
  for (int r = 0; r < 4; r++) {
    float s = 0.f;
#pragma unroll
    for (int ct = 0; ct < 10; ct++) {
      float a = acc2[ct][r] + b2v[ct];
      s = fmaf(fmaxf(a, 0.f), w3v[ct], s);
    }
    s += __shfl_xor(s, 1, 64);
    s += __shfl_xor(s, 2, 64);
    s += __shfl_xor(s, 4, 64);
    s += __shfl_xor(s, 8, 64);
    if (c == 0) {
      int p = tbase + wave * 16 + g * 4 + r;
      if (p < P) {
        float val = s + ms[im[r]] + ms[jm[r]] + b3v;
        ((float2*)out2)[p] = make_float2(0.f, val);
      }
    }
  }
}

// ---------------------------------------------------------------------------
// per-group softmax rows (wave per row) — unchanged, known good
// ---------------------------------------------------------------------------
__global__ __launch_bounds__(64, 1)
void softmax_rows(const float* __restrict__ out2,
                  float* __restrict__ probs, int G) {
  int b = blockIdx.x;
  int t = threadIdx.x;
  if (b == 0) {
    for (int pos = t; pos <= KMAX; pos += 64)
      probs[pos] = (pos == 0) ? 1.0f : 1000.0f;
    return;
  }
  int g = b - 1;
  int L = (g + 1 < KMAX) ? g + 1 : KMAX;
  int base = (g <= KMAX) ? g * (g + 1) / 2
                         : KMAX * (KMAX + 1) / 2 + (g - KMAX) * KMAX;
  float mx = 0.f;
  for (int pos = t; pos < L; pos += 64)
    mx = fmaxf(mx, out2[2 * (base + pos) + 1]);
#pragma unroll
  for (int off = 32; off >= 1; off >>= 1) mx = fmaxf(mx, __shfl_xor(mx, off));

  float sum = (t == 0) ? expf(-mx) : 0.f;
  for (int pos = t; pos < L; pos += 64)
    sum += expf(out2[2 * (base + pos) + 1] - mx);
#pragma unroll
  for (int off = 32; off >= 1; off >>= 1) sum += __shfl_xor(sum, off);
  float inv = 1.f / sum;

  float* row = probs + (size_t)(g + 1) * (KMAX + 1);
  for (int pos = t; pos <= KMAX; pos += 64) {
    float v;
    if (pos < L)       v = expf(out2[2 * (base + pos) + 1] - mx) * inv;
    else if (pos == L) v = expf(-mx) * inv;
    else               v = 1000.0f;
    row[pos] = v;
  }
}

// ---------------------------------------------------------------------------
extern "C" void kernel_launch(void* const* d_in, const int* in_sizes, int n_in,
                              void* d_out, int out_size, void* d_ws, size_t ws_size,
                              hipStream_t stream) {
  const float* g_i        = (const float*)d_in[0];
  const float* ms         = (const float*)d_in[1];
  const float* dist_embed = (const float*)d_in[2];
  const float* W1         = (const float*)d_in[3];
  const float* b1         = (const float*)d_in[4];
  const float* W2         = (const float*)d_in[5];
  const float* b2         = (const float*)d_in[6];
  const float* W3         = (const float*)d_in[7];
  const float* b3         = (const float*)d_in[8];
  const int* mid          = (const int*)d_in[9];
  const int* aid          = (const int*)d_in[10];
  const int* dist         = (const int*)d_in[11];

  int N = in_sizes[0] / GDIM;     // 2000
  int P = in_sizes[9];            // 468625
  int G = in_sizes[14];           // 1999

  float* wsf   = (float*)d_ws;
  float* probs = (float*)d_out;
  float* out2  = (float*)d_out + (size_t)(G + 1) * (KMAX + 1);

  int tot_uv = 2 * N * HP;
  precompute_uv<<<(tot_uv + 255) / 256, 256, 0, stream>>>(g_i, W1, b1, wsf, N);
  int tot_tab = 9 * HP + 2 * HP + NCH * CH_SH;
  precompute_tabs<<<(tot_tab + 255) / 256, 256, 0, stream>>>(dist_embed, W1, W2, b2, W3, wsf);
  pair_mlp<<<(P + 127) / 128, 512, 0, stream>>>(g_i, ms, mid, aid, dist, b3, wsf, out2, P);
  softmax_rows<<<G + 1, 64, 0, stream>>>(out2, probs, G);
}

// Round 11
// 295.777 us; speedup vs baseline: 13.3501x; 1.1926x over previous
//
#include <hip/hip_runtime.h>
#include <hip/hip_bf16.h>

#define GDIM 256
#define HID 150
#define HP 160
#define KMAX 250
#define NMAX 2000

typedef __attribute__((ext_vector_type(8))) short bf16x8;
typedef __attribute__((ext_vector_type(4))) float f32x4;

// float ws region
#define FU   0
#define FV   (FU + NMAX*HP)
#define FD   (FV + NMAX*HP)
#define FW3  (FD + 9*HP)
#define FB2  (FW3 + HP)
#define FEND (FB2 + HP)              // 641760 floats
// ushort region: 7 B-chunks. Chunks 0-5: [160 n][64 k] bf16 = 10240 shorts,
// swizzled within 128-B rows: stored_byte = logical_byte ^ ((n&7)<<4).
// Chunk 6 (W2 tail, K=32): [160][32] = 5120 shorts, stored_byte ^= ((n&3)<<4).
// Chunks 0-3 = WcT (K=256); 4-5 = W2T k<128; 6 = W2T k 128..159.
#define CHFULL 10240
#define UBTOT  66560

static __device__ __forceinline__ short cvt_bf(float x) {
  __hip_bfloat16 h = __float2bfloat16(x);
  return *reinterpret_cast<short*>(&h);
}

// async global->LDS, 16 B/lane (LDS dest = wave-uniform base + lane*16)
static __device__ __forceinline__ void gl_lds16(const void* g, void* l) {
  __builtin_amdgcn_global_load_lds(
      (const __attribute__((address_space(1))) unsigned int*)g,
      (__attribute__((address_space(3))) unsigned int*)l, 16, 0, 0);
}

// stage nseg KB-segments, 4 waves cooperating
static __device__ __forceinline__ void stage_chunk(const unsigned short* src, short* dst,
                                                   int nseg, int wave, int lane) {
  const char* s = (const char*)src;
  char* d = (char*)dst;
  for (int seg = wave; seg < nseg; seg += 4)
    gl_lds16(s + seg * 1024 + lane * 16, d + seg * 1024);
}

// ---------------------------------------------------------------------------
// U[i] = i_g @ W1[0:256] + b1 ; V[j] = j_g @ W1[256:512]  (fp32, 4 cols/thread)
// ---------------------------------------------------------------------------
__global__ void precompute_uv(const float* __restrict__ g_i,
                              const float* __restrict__ W1,
                              const float* __restrict__ b1,
                              float* __restrict__ ws, int N) {
  int t = blockIdx.x * blockDim.x + threadIdx.x;
  int total = N * (HP / 4);
  bool isV = false;
  if (t >= total) { t -= total; isV = true; }
  if (t >= total) return;
  int r = t / (HP / 4), c4 = (t - r * (HP / 4)) * 4;
  float a0 = 0.f, a1 = 0.f, a2 = 0.f, a3 = 0.f;
  if (c4 < HID) {
    const float* w = W1 + (isV ? GDIM * HID : 0) + c4;
    const float* g = g_i + (size_t)r * GDIM;
#pragma unroll 4
    for (int k = 0; k < GDIM; k++) {
      float gv = g[k];
      const float* wr = w + (size_t)k * HID;
      a0 = fmaf(gv, wr[0], a0);
      a1 = fmaf(gv, wr[1], a1);
      a2 = fmaf(gv, wr[2], a2);
      a3 = fmaf(gv, wr[3], a3);     // c4=148: cols 150/151 read into next row (valid mem), discarded below
    }
    if (!isV) {
      a0 += b1[c4];
      if (c4 + 1 < HID) a1 += b1[c4 + 1];
      if (c4 + 2 < HID) a2 += b1[c4 + 2];
      if (c4 + 3 < HID) a3 += b1[c4 + 3];
    }
  }
  float* dst = ws + (isV ? FV : FU) + (size_t)r * HP + c4;
  dst[0] = (c4     < HID) ? a0 : 0.f;
  dst[1] = (c4 + 1 < HID) ? a1 : 0.f;
  dst[2] = (c4 + 2 < HID) ? a2 : 0.f;
  dst[3] = (c4 + 3 < HID) ? a3 : 0.f;
}

// ---------------------------------------------------------------------------
// D table, W3/b2 fp32 pads, and the 7 pre-swizzled bf16 B-chunks
// ---------------------------------------------------------------------------
__global__ void precompute_tabs(const float* __restrict__ dist_embed,
                                const float* __restrict__ W1,
                                const float* __restrict__ W2,
                                const float* __restrict__ b2,
                                const float* __restrict__ W3,
                                float* __restrict__ wsf) {
  unsigned short* wsu = (unsigned short*)(wsf + FEND);
  int t = blockIdx.x * blockDim.x + threadIdx.x;
  if (t < 9 * HP) {                                    // D[d][c]
    int d = t / HP, c = t - d * HP;
    float a = 0.f;
    if (c < HID) {
#pragma unroll
      for (int k = 0; k < 20; k++)
        a = fmaf(dist_embed[d * 20 + k], W1[(size_t)(768 + k) * HID + c], a);
    }
    wsf[FD + t] = a;
    return;
  }
  t -= 9 * HP;
  if (t < HP) { wsf[FW3 + t] = (t < HID) ? W3[t] : 0.f; return; }
  t -= HP;
  if (t < HP) { wsf[FB2 + t] = (t < HID) ? b2[t] : 0.f; return; }
  t -= HP;
  if (t < UBTOT) {
    int ch, s;
    if (t < 6 * CHFULL) { ch = t / CHFULL; s = t - ch * CHFULL; }
    else                { ch = 6; s = t - 6 * CHFULL; }
    int n, kl;
    if (ch < 6) { n = s >> 6; kl = (s & 63) ^ ((n & 7) << 3); }
    else        { n = s >> 5; kl = (s & 31) ^ ((n & 3) << 3); }
    float w = 0.f;
    if (ch < 4) {
      int k = ch * 64 + kl;                            // WcT[n][k] = W1[512+k][n]
      if (n < HID) w = W1[(size_t)(2 * GDIM + k) * HID + n];
    } else {
      int k = (ch - 4) * 64 + kl;                      // W2T[n][k] = W2[k][n]
      if (n < HID && k < HID) w = W2[(size_t)k * HID + n];
    }
    wsu[t] = (unsigned short)cvt_bf(w);
    return;
  }
}

// ---------------------------------------------------------------------------
// Pair MLP: 256 threads = 4 waves, 32 pairs/wave (2 A row-tiles), 128/block.
// B via LDS double-buffered K=64 chunks (7 barriers vs 13), A prefetched into
// registers one chunk ahead (T14), setprio around MFMA clusters (T5).
// 2 blocks/CU (LDS 2x81920 = 160 KiB exactly) decouple barrier convoys.
// ---------------------------------------------------------------------------
__global__ __launch_bounds__(256, 2)
void pair_mlp(const float* __restrict__ g_i,
              const float* __restrict__ ms,
              const int* __restrict__ mid,
              const int* __restrict__ aid,
              const int* __restrict__ dist,
              const float* __restrict__ b3,
              const float* __restrict__ wsf,
              float* __restrict__ out2, int P) {
  __shared__ short Bb[2][CHFULL];      // 2 x 20480 B chunk buffers
  __shared__ short Hh[4][5120];        // per-wave H: 32 rows x 320 B
  const unsigned short* UB = (const unsigned short*)(wsf + FEND);

  int tid = threadIdx.x;
  int wave = tid >> 6, lane = tid & 63;
  int c = lane & 15, g = lane >> 4;
  int tbase = blockIdx.x * 128 + wave * 32;

  int p0 = tbase + c;      if (p0 >= P) p0 = P - 1;
  int p1 = tbase + 16 + c; if (p1 >= P) p1 = P - 1;
  const float* gI0 = g_i + (size_t)mid[p0] * GDIM;
  const float* gJ0 = g_i + (size_t)aid[p0] * GDIM;
  const float* gI1 = g_i + (size_t)mid[p1] * GDIM;
  const float* gJ1 = g_i + (size_t)aid[p1] * GDIM;

  int xr7 = (c & 7) << 4;
  int xr3 = (c & 3) << 4;
  int nb[10];
#pragma unroll
  for (int ct = 0; ct < 10; ct++) nb[ct] = (16 * ct + c) * 128;
  int ko[2] = { (g * 16) ^ xr7, (64 + g * 16) ^ xr7 };

  float pfv[64];                       // A prefetch: [mt*2+k2]*16 + {i:0-7, j:8-15}
  bf16x8 Af[2][2];

#define PF_LOAD(T) do {                                                        \
    int kb = (T) * 64 + g * 8;                                                 \
    _Pragma("unroll")                                                          \
    for (int mt = 0; mt < 2; mt++) {                                           \
      const float* pi = mt ? gI1 : gI0;                                        \
      const float* pj = mt ? gJ1 : gJ0;                                        \
      _Pragma("unroll")                                                        \
      for (int k2 = 0; k2 < 2; k2++) {                                         \
        int kk = kb + k2 * 32;                                                 \
        int bs = (mt * 2 + k2) * 16;                                           \
        *(float4*)&pfv[bs + 0]  = *(const float4*)(pi + kk);                   \
        *(float4*)&pfv[bs + 4]  = *(const float4*)(pi + kk + 4);               \
        *(float4*)&pfv[bs + 8]  = *(const float4*)(pj + kk);                   \
        *(float4*)&pfv[bs + 12] = *(const float4*)(pj + kk + 4);               \
      }                                                                        \
    }                                                                          \
  } while (0)

#define PF_CVT() do {                                                          \
    _Pragma("unroll")                                                          \
    for (int mt = 0; mt < 2; mt++)                                             \
    _Pragma("unroll")                                                          \
    for (int k2 = 0; k2 < 2; k2++) {                                           \
      int bs = (mt * 2 + k2) * 16;                                             \
      _Pragma("unroll")                                                        \
      for (int e = 0; e < 8; e++)                                              \
        Af[mt][k2][e] = cvt_bf(pfv[bs + e] * pfv[bs + 8 + e]);                 \
    }                                                                          \
  } while (0)

  // ---- prologue: prefetch A chunk0, stage B chunk0 ----
  PF_LOAD(0);
  stage_chunk(UB, &Bb[0][0], 20, wave, lane);
  __syncthreads();

  f32x4 acc[2][10];
#pragma unroll
  for (int mt = 0; mt < 2; mt++)
#pragma unroll
    for (int ct = 0; ct < 10; ct++) acc[mt][ct] = (f32x4){0.f, 0.f, 0.f, 0.f};

  // ================= GEMM1: 4 chunks of K=64 =================
#pragma unroll
  for (int t = 0; t < 4; t++) {
    PF_CVT();
    if (t < 3) PF_LOAD(t + 1);
    stage_chunk(UB + (size_t)(t + 1) * CHFULL, &Bb[(t + 1) & 1][0], 20, wave, lane);
    const char* Bp = (const char*)&Bb[t & 1][0];
    __builtin_amdgcn_s_setprio(1);
#pragma unroll
    for (int k2 = 0; k2 < 2; k2++)
#pragma unroll
      for (int ct = 0; ct < 10; ct++) {
        bf16x8 Bf = *(const bf16x8*)(Bp + nb[ct] + ko[k2]);
        acc[0][ct] = __builtin_amdgcn_mfma_f32_16x16x32_bf16(Af[0][k2], Bf, acc[0][ct], 0, 0, 0);
        acc[1][ct] = __builtin_amdgcn_mfma_f32_16x16x32_bf16(Af[1][k2], Bf, acc[1][ct], 0, 0, 0);
      }
    __builtin_amdgcn_s_setprio(0);
    __syncthreads();
  }

  // ---- epilogue 1: bias + relu -> H (regionally-bijective XOR, r10-verified)
  int im[2][4], jm[2][4], dm[2][4];
#pragma unroll
  for (int mt = 0; mt < 2; mt++)
#pragma unroll
    for (int r = 0; r < 4; r++) {
      int p = tbase + mt * 16 + 4 * g + r;
      int pc = (p < P) ? p : (P - 1);
      im[mt][r] = mid[pc]; jm[mt][r] = aid[pc];
      int d = dist[pc];
      dm[mt][r] = (d >= 1) + (d >= 2) + (d >= 3) + (d >= 4) +
                  (d >= 8) + (d >= 16) + (d >= 32) + (d >= 64);
    }
  const float* Ut = wsf + FU;
  const float* Vt = wsf + FV;
  const float* Dt = wsf + FD;
  char* Hw = (char*)&Hh[wave][0];
#pragma unroll
  for (int mt = 0; mt < 2; mt++)
#pragma unroll
    for (int ct = 0; ct < 10; ct++)
#pragma unroll
      for (int r = 0; r < 4; r++) {
        int col = 16 * ct + c;
        float bias = Ut[(size_t)im[mt][r] * HP + col] +
                     Vt[(size_t)jm[mt][r] * HP + col] +
                     Dt[dm[mt][r] * HP + col];
        float h = fmaxf(acc[mt][ct][r] + bias, 0.f);
        int row = mt * 16 + 4 * g + r;
        int byte = 32 * ct + 2 * c;
        int bo = (byte < 256) ? (byte ^ ((row & 7) << 4))
                              : (256 + ((byte - 256) ^ ((row & 3) << 4)));
        *(short*)(Hw + row * 320 + bo) = cvt_bf(h);
      }

  // ================= GEMM2: 2 chunks K=64 + tail K=32 =================
  f32x4 acc2[2][10];
#pragma unroll
  for (int mt = 0; mt < 2; mt++)
#pragma unroll
    for (int ct = 0; ct < 10; ct++) acc2[mt][ct] = (f32x4){0.f, 0.f, 0.f, 0.f};

  const char* Hc = (const char*)&Hh[wave][0];
  bf16x8 A2[2][2];

#define H_FRAG(MT, K2, KS) do {                                                \
    int row = (MT) * 16 + c;                                                   \
    int byte = (KS) * 128 + (K2) * 64 + g * 16;                                \
    int bo = (byte < 256) ? (byte ^ ((row & 7) << 4))                          \
                          : (256 + ((byte - 256) ^ ((row & 3) << 4)));         \
    A2[MT][K2] = *(const bf16x8*)(Hc + row * 320 + bo);                        \
  } while (0)

  // ks = 0 (chunk4 in Bb[0]); stage chunk5 -> Bb[1]
  stage_chunk(UB + (size_t)5 * CHFULL, &Bb[1][0], 20, wave, lane);
  H_FRAG(0, 0, 0); H_FRAG(0, 1, 0); H_FRAG(1, 0, 0); H_FRAG(1, 1, 0);
  {
    const char* Bp = (const char*)&Bb[0][0];
    __builtin_amdgcn_s_setprio(1);
#pragma unroll
    for (int k2 = 0; k2 < 2; k2++)
#pragma unroll
      for (int ct = 0; ct < 10; ct++) {
        bf16x8 Bf = *(const bf16x8*)(Bp + nb[ct] + ko[k2]);
        acc2[0][ct] = __builtin_amdgcn_mfma_f32_16x16x32_bf16(A2[0][k2], Bf, acc2[0][ct], 0, 0, 0);
        acc2[1][ct] = __builtin_amdgcn_mfma_f32_16x16x32_bf16(A2[1][k2], Bf, acc2[1][ct], 0, 0, 0);
      }
    __builtin_amdgcn_s_setprio(0);
  }
  __syncthreads();

  // ks = 1 (chunk5 in Bb[1]); stage chunk6 -> Bb[0] (10 segs)
  stage_chunk(UB + (size_t)6 * CHFULL, &Bb[0][0], 10, wave, lane);
  H_FRAG(0, 0, 1); H_FRAG(0, 1, 1); H_FRAG(1, 0, 1); H_FRAG(1, 1, 1);
  {
    const char* Bp = (const char*)&Bb[1][0];
    __builtin_amdgcn_s_setprio(1);
#pragma unroll
    for (int k2 = 0; k2 < 2; k2++)
#pragma unroll
      for (int ct = 0; ct < 10; ct++) {
        bf16x8 Bf = *(const bf16x8*)(Bp + nb[ct] + ko[k2]);
        acc2[0][ct] = __builtin_amdgcn_mfma_f32_16x16x32_bf16(A2[0][k2], Bf, acc2[0][ct], 0, 0, 0);
        acc2[1][ct] = __builtin_amdgcn_mfma_f32_16x16x32_bf16(A2[1][k2], Bf, acc2[1][ct], 0, 0, 0);
      }
    __builtin_amdgcn_s_setprio(0);
  }
  __syncthreads();

  // ks = 2 tail (chunk6 in Bb[0], K=32, row stride 64 B)
  H_FRAG(0, 0, 2); H_FRAG(1, 0, 2);
  {
    const char* Bp = (const char*)&Bb[0][0];
    int koT = (g * 16) ^ xr3;
    __builtin_amdgcn_s_setprio(1);
#pragma unroll
    for (int ct = 0; ct < 10; ct++) {
      bf16x8 Bf = *(const bf16x8*)(Bp + (16 * ct + c) * 64 + koT);
      acc2[0][ct] = __builtin_amdgcn_mfma_f32_16x16x32_bf16(A2[0][0], Bf, acc2[0][ct], 0, 0, 0);
      acc2[1][ct] = __builtin_amdgcn_mfma_f32_16x16x32_bf16(A2[1][0], Bf, acc2[1][ct], 0, 0, 0);
    }
    __builtin_amdgcn_s_setprio(0);
  }

  // ---- epilogue 2: +b2, relu, dot W3, reduce over c, store ----
  float b2v[10], w3v[10];
#pragma unroll
  for (int ct = 0; ct < 10; ct++) {
    b2v[ct] = wsf[FB2 + 16 * ct + c];
    w3v[ct] = wsf[FW3 + 16 * ct + c];
  }
  float b3v = b3[0];
#pragma unroll
  for (int mt = 0; mt < 2; mt++)
#pragma unroll
    for (int r = 0; r < 4; r++) {
      float s = 0.f;
#pragma unroll
      for (int ct = 0; ct < 10; ct++) {
        float a = acc2[mt][ct][r] + b2v[ct];
        s = fmaf(fmaxf(a, 0.f), w3v[ct], s);
      }
      s += __shfl_xor(s, 1, 64);
      s += __shfl_xor(s, 2, 64);
      s += __shfl_xor(s, 4, 64);
      s += __shfl_xor(s, 8, 64);
      if (c == 0) {
        int p = tbase + mt * 16 + 4 * g + r;
        if (p < P) {
          float val = s + ms[im[mt][r]] + ms[jm[mt][r]] + b3v;
          ((float2*)out2)[p] = make_float2(0.f, val);
        }
      }
    }
#undef PF_LOAD
#undef PF_CVT
#undef H_FRAG
}

// ---------------------------------------------------------------------------
// per-group softmax rows (wave per row) — unchanged, known good
// ---------------------------------------------------------------------------
__global__ __launch_bounds__(64, 1)
void softmax_rows(const float* __restrict__ out2,
                  float* __restrict__ probs, int G) {
  int b = blockIdx.x;
  int t = threadIdx.x;
  if (b == 0) {
    for (int pos = t; pos <= KMAX; pos += 64)
      probs[pos] = (pos == 0) ? 1.0f : 1000.0f;
    return;
  }
  int g = b - 1;
  int L = (g + 1 < KMAX) ? g + 1 : KMAX;
  int base = (g <= KMAX) ? g * (g + 1) / 2
                         : KMAX * (KMAX + 1) / 2 + (g - KMAX) * KMAX;
  float mx = 0.f;
  for (int pos = t; pos < L; pos += 64)
    mx = fmaxf(mx, out2[2 * (base + pos) + 1]);
#pragma unroll
  for (int off = 32; off >= 1; off >>= 1) mx = fmaxf(mx, __shfl_xor(mx, off));

  float sum = (t == 0) ? expf(-mx) : 0.f;
  for (int pos = t; pos < L; pos += 64)
    sum += expf(out2[2 * (base + pos) + 1] - mx);
#pragma unroll
  for (int off = 32; off >= 1; off >>= 1) sum += __shfl_xor(sum, off);
  float inv = 1.f / sum;

  float* row = probs + (size_t)(g + 1) * (KMAX + 1);
  for (int pos = t; pos <= KMAX; pos += 64) {
    float v;
    if (pos < L)       v = expf(out2[2 * (base + pos) + 1] - mx) * inv;
    else if (pos == L) v = expf(-mx) * inv;
    else               v = 1000.0f;
    row[pos] = v;
  }
}

// ---------------------------------------------------------------------------
extern "C" void kernel_launch(void* const* d_in, const int* in_sizes, int n_in,
                              void* d_out, int out_size, void* d_ws, size_t ws_size,
                              hipStream_t stream) {
  const float* g_i        = (const float*)d_in[0];
  const float* ms         = (const float*)d_in[1];
  const float* dist_embed = (const float*)d_in[2];
  const float* W1         = (const float*)d_in[3];
  const float* b1         = (const float*)d_in[4];
  const float* W2         = (const float*)d_in[5];
  const float* b2         = (const float*)d_in[6];
  const float* W3         = (const float*)d_in[7];
  const float* b3         = (const float*)d_in[8];
  const int* mid          = (const int*)d_in[9];
  const int* aid          = (const int*)d_in[10];
  const int* dist         = (const int*)d_in[11];

  int N = in_sizes[0] / GDIM;     // 2000
  int P = in_sizes[9];            // 468625
  int G = in_sizes[14];           // 1999

  float* wsf   = (float*)d_ws;
  float* probs = (float*)d_out;
  float* out2  = (float*)d_out + (size_t)(G + 1) * (KMAX + 1);

  int tot_uv = 2 * N * (HP / 4);
  precompute_uv<<<(tot_uv + 255) / 256, 256, 0, stream>>>(g_i, W1, b1, wsf, N);
  int tot_tab = 9 * HP + 2 * HP + UBTOT;
  precompute_tabs<<<(tot_tab + 255) / 256, 256, 0, stream>>>(dist_embed, W1, W2, b2, W3, wsf);
  pair_mlp<<<(P + 127) / 128, 256, 0, stream>>>(g_i, ms, mid, aid, dist, b3, wsf, out2, P);
  softmax_rows<<<G + 1, 64, 0, stream>>>(out2, probs, G);
}